// Round 1
// baseline (1251.252 us; speedup 1.0000x reference)
//
#include <hip/hip_runtime.h>
#include <stdint.h>

// ManualLSTM: B=512, T=1024, D=64, U=128.
// Persistent-block fused LSTM: 64 blocks x 1024 threads, 8 batch rows/block.
// Recurrent+input GEMM per step via bf16 MFMA 16x16x32 (fp32 accumulate),
// weights resident in VGPR B-fragments, h/x staged in LDS, c in registers.

typedef __attribute__((ext_vector_type(8))) short short8;
typedef __attribute__((ext_vector_type(4))) float floatx4;

#define B_SZ   512
#define T_SZ   1024
#define D_SZ   64
#define U_SZ   128
#define KTOT   192          // D + U
#define ROWS   8            // batch rows per block
#define NBLK   (B_SZ / ROWS)  // 64 blocks
#define NTHR   1024         // 16 waves
#define ASTR   200          // A-tile row stride in bf16 elems (192 + 8 pad; 400B = 16B-aligned, 2-way-bank free)
#define GSTR   516          // G-buffer row stride in fp32 (512 + 4 pad)

__device__ __forceinline__ short f2bf(float f) {
    uint32_t u = __builtin_bit_cast(uint32_t, f);
    uint32_t r = (u + 0x7fffu + ((u >> 16) & 1u)) >> 16;   // RNE
    return (short)r;
}

__device__ __forceinline__ float fsig(float x) {
    // 1/(1+2^(-x*log2e))
    return __builtin_amdgcn_rcpf(1.0f + __builtin_amdgcn_exp2f(-1.4426950408889634f * x));
}
__device__ __forceinline__ float ftanh(float x) {
    // 1 - 2/(2^(2x*log2e)+1); saturates correctly at +-inf
    return 1.0f - 2.0f * __builtin_amdgcn_rcpf(1.0f + __builtin_amdgcn_exp2f(2.8853900817779268f * x));
}

__global__ __launch_bounds__(NTHR) void lstm_persistent(
    const float* __restrict__ xin,
    const float* __restrict__ Wf, const float* __restrict__ Uf, const float* __restrict__ bfp,
    const float* __restrict__ Wi, const float* __restrict__ Ui, const float* __restrict__ bip,
    const float* __restrict__ Wc, const float* __restrict__ Uc, const float* __restrict__ bcp,
    const float* __restrict__ Wo, const float* __restrict__ Uo, const float* __restrict__ bop,
    float* __restrict__ out)
{
    __shared__ short Abuf[16 * ASTR];       // [m=0..15][k=0..191] bf16; rows 8..15 are zero pad
    __shared__ float Gbuf[ROWS * GSTR];     // gate pre-activations, fp32

    const int tid  = threadIdx.x;
    const int wave = tid >> 6;      // 0..15
    const int lane = tid & 63;
    const int quad = lane >> 4;     // 0..3
    const int nlo  = lane & 15;
    const int blk  = blockIdx.x;

    // ---- load static weight B-fragments into VGPRs (once) ----
    // wave w owns N-tiles {2w, 2w+1} -> columns [32w, 32w+32) of the 512 gate cols
    // B layout (16x16x32): B[k = quad*8 + j][n = lane&15]
    short8 bfr[2][6];
#pragma unroll
    for (int ti = 0; ti < 2; ++ti) {
        int col  = (2 * wave + ti) * 16 + nlo;   // 0..511
        int gate = col >> 7;                      // wave-uniform per tile
        int u    = col & 127;
        const float* Wp = (gate == 0) ? Wf : (gate == 1) ? Wi : (gate == 2) ? Wc : Wo;
        const float* Up = (gate == 0) ? Uf : (gate == 1) ? Ui : (gate == 2) ? Uc : Uo;
#pragma unroll
        for (int kt = 0; kt < 6; ++kt) {
#pragma unroll
            for (int j = 0; j < 8; ++j) {
                int k = kt * 32 + quad * 8 + j;   // 0..191
                float w = (k < 64) ? Wp[k * U_SZ + u] : Up[(k - 64) * U_SZ + u];
                bfr[ti][kt][j] = f2bf(w);
            }
        }
    }

    // ---- per-thread nonlinearity assignment: exactly one (row,u) pair ----
    const int nrow = tid >> 7;      // 0..7
    const int nu   = tid & 127;     // 0..127
    const float bF = bfp[nu], bI = bip[nu], bC = bcp[nu], bO = bop[nu];
    float c_st = 0.0f;              // cell state for (nrow, nu)

    // ---- zero A (covers h(0)=0 and the M-pad rows 8..15) ----
    for (int i = tid; i < 16 * ASTR; i += NTHR) Abuf[i] = 0;
    __syncthreads();

    // ---- x staging: threads 0..511 handle (row6 = tid>>6, d6 = tid&63) ----
    const int row6 = tid >> 6;              // valid 0..7 for tid<512
    const int d6   = tid & 63;
    const float* xbase = xin + ((size_t)(blk * ROWS + (row6 & 7)) * T_SZ) * D_SZ + d6;
    float xv0 = 0.0f, xv1 = 0.0f;
    if (tid < 512) {
        Abuf[row6 * ASTR + d6] = f2bf(xbase[0]);        // x(0)
        xv0 = xbase[1 * D_SZ];                           // x(1)
        xv1 = xbase[2 * D_SZ];                           // x(2)
    }
    __syncthreads();

    const short* arow = &Abuf[nlo * ASTR + quad * 8];   // A[m=lane&15][k = quad*8 + kt*32 + j]

    for (int t = 0; t < T_SZ; ++t) {
        // prefetch x(t+3) (depth-2 pipeline; clamp tail, values discarded)
        float xnext = 0.0f;
        if (tid < 512) {
            int tt = t + 3; if (tt > T_SZ - 1) tt = T_SZ - 1;
            xnext = xbase[tt * D_SZ];
        }

        // ---- MFMA: G[16,512] += A[16,192] * Wc[192,512] (this wave: 2 N-tiles) ----
        short8 a[6];
#pragma unroll
        for (int kt = 0; kt < 6; ++kt)
            a[kt] = *(const short8*)(arow + kt * 32);
        floatx4 acc0 = {0.f, 0.f, 0.f, 0.f};
        floatx4 acc1 = {0.f, 0.f, 0.f, 0.f};
#pragma unroll
        for (int kt = 0; kt < 6; ++kt) {
            acc0 = __builtin_amdgcn_mfma_f32_16x16x32_bf16(a[kt], bfr[0][kt], acc0, 0, 0, 0);
            acc1 = __builtin_amdgcn_mfma_f32_16x16x32_bf16(a[kt], bfr[1][kt], acc1, 0, 0, 0);
        }

        // ---- write valid gate rows (0..7) to LDS; C/D layout: col=lane&15, row=quad*4+reg ----
        if (quad < 2) {
#pragma unroll
            for (int r = 0; r < 4; ++r) {
                int row = quad * 4 + r;
                Gbuf[row * GSTR + (2 * wave + 0) * 16 + nlo] = acc0[r];
                Gbuf[row * GSTR + (2 * wave + 1) * 16 + nlo] = acc1[r];
            }
        }
        __syncthreads();

        // ---- nonlinearity + state update: one (row,u) pair per thread ----
        {
            float gf = Gbuf[nrow * GSTR +       nu] + bF;
            float gi = Gbuf[nrow * GSTR + 128 + nu] + bI;
            float gc = Gbuf[nrow * GSTR + 256 + nu] + bC;
            float go = Gbuf[nrow * GSTR + 384 + nu] + bO;
            float f  = fsig(gf);
            float ii = fsig(gi);
            float oo = fsig(go);
            float ct = ftanh(gc);
            c_st = f * c_st + ii * ct;
            float h = oo * ftanh(c_st);
            if (t == T_SZ - 1) {
                out[(size_t)(blk * ROWS + nrow) * U_SZ + nu] = h;
            } else {
                Abuf[nrow * ASTR + 64 + nu] = f2bf(h);   // h(t+1) into A's K=64..191 region
            }
        }
        // stage x(t+1) into A's K=0..63 region
        if (tid < 512 && t < T_SZ - 1) {
            Abuf[row6 * ASTR + d6] = f2bf(xv0);
        }
        xv0 = xv1;
        xv1 = xnext;
        __syncthreads();
    }
}

extern "C" void kernel_launch(void* const* d_in, const int* in_sizes, int n_in,
                              void* d_out, int out_size, void* d_ws, size_t ws_size,
                              hipStream_t stream) {
    (void)in_sizes; (void)n_in; (void)d_ws; (void)ws_size; (void)out_size;
    const float* xin = (const float*)d_in[0];
    const float* Wf  = (const float*)d_in[1];
    const float* Uf  = (const float*)d_in[2];
    const float* bf  = (const float*)d_in[3];
    const float* Wi  = (const float*)d_in[4];
    const float* Ui  = (const float*)d_in[5];
    const float* bi  = (const float*)d_in[6];
    const float* Wc  = (const float*)d_in[7];
    const float* Uc  = (const float*)d_in[8];
    const float* bc  = (const float*)d_in[9];
    const float* Wo  = (const float*)d_in[10];
    const float* Uo  = (const float*)d_in[11];
    const float* bo  = (const float*)d_in[12];
    float* out = (float*)d_out;

    hipLaunchKernelGGL(lstm_persistent, dim3(NBLK), dim3(NTHR), 0, stream,
                       xin, Wf, Uf, bf, Wi, Ui, bi, Wc, Uc, bc, Wo, Uo, bo, out);
}

// Round 2
// 1006.111 us; speedup vs baseline: 1.2437x; 1.2437x over previous
//
#include <hip/hip_runtime.h>
#include <stdint.h>

// ManualLSTM: B=512, T=1024, D=64, U=128.
// 64 blocks x 512 threads (8 waves), 8 batch rows/block, persistent over all T.
// Gate-interleaved N ownership: wave w owns u in [16w,16w+16) for ALL 4 gates
// (4 MFMA N-tiles), so gate pre-activations never round-trip through LDS.
// Double-buffered A (x||h, bf16) + ONE lgkmcnt-only barrier per step
// (no vmcnt drain -> x HBM prefetch stays in flight across the barrier).

typedef __attribute__((ext_vector_type(8))) short short8;
typedef __attribute__((ext_vector_type(4))) float floatx4;

#define B_SZ   512
#define T_SZ   1024
#define D_SZ   64
#define U_SZ   128
#define ROWS   8              // batch rows per block
#define NBLK   (B_SZ / ROWS)  // 64 blocks
#define NTHR   512            // 8 waves
#define ASTR   200            // A row stride in bf16 (192 + 8 pad; rows stay 16B-aligned)

__device__ __forceinline__ short f2bf(float f) {
    uint32_t u = __builtin_bit_cast(uint32_t, f);
    uint32_t r = (u + 0x7fffu + ((u >> 16) & 1u)) >> 16;   // RNE
    return (short)r;
}

__device__ __forceinline__ float fsig(float x) {
    return __builtin_amdgcn_rcpf(1.0f + __builtin_amdgcn_exp2f(-1.4426950408889634f * x));
}
__device__ __forceinline__ float ftanh(float x) {
    return 1.0f - 2.0f * __builtin_amdgcn_rcpf(1.0f + __builtin_amdgcn_exp2f(2.8853900817779268f * x));
}

// barrier that drains only LDS ops (NOT vmcnt -> global x prefetch stays in flight)
__device__ __forceinline__ void sync_lds() {
    asm volatile("s_waitcnt lgkmcnt(0)\n\ts_barrier" ::: "memory");
}

__global__ __launch_bounds__(NTHR) void lstm_persistent(
    const float* __restrict__ xin,
    const float* __restrict__ Wf, const float* __restrict__ Uf, const float* __restrict__ bfp,
    const float* __restrict__ Wi, const float* __restrict__ Ui, const float* __restrict__ bip,
    const float* __restrict__ Wc, const float* __restrict__ Uc, const float* __restrict__ bcp,
    const float* __restrict__ Wo, const float* __restrict__ Uo, const float* __restrict__ bop,
    float* __restrict__ out)
{
    __shared__ short Abuf[2][16 * ASTR];   // [buf][m=0..15][k=0..191] bf16; rows 8..15 zero pad

    const int tid  = threadIdx.x;
    const int wave = tid >> 6;     // 0..7
    const int lane = tid & 63;
    const int quad = lane >> 4;    // 0..3
    const int nlo  = lane & 15;
    const int blk  = blockIdx.x;

    const int u = 16 * wave + nlo; // this lane's hidden-unit column, 0..127

    // ---- static weight B-fragments in VGPRs: bfr[gate][kt] ----
    // B layout (16x16x32): B[k = quad*8 + j][n = lane&15]; col n <-> u = 16*wave + n
    const float* Wg[4] = {Wf, Wi, Wc, Wo};
    const float* Ug[4] = {Uf, Ui, Uc, Uo};
    short8 bfr[4][6];
#pragma unroll
    for (int g = 0; g < 4; ++g) {
#pragma unroll
        for (int kt = 0; kt < 6; ++kt) {
#pragma unroll
            for (int j = 0; j < 8; ++j) {
                int k = kt * 32 + quad * 8 + j;   // 0..191
                float w = (k < D_SZ) ? Wg[g][k * U_SZ + u] : Ug[g][(k - D_SZ) * U_SZ + u];
                bfr[g][kt][j] = f2bf(w);
            }
        }
    }
    const float bias[4] = {bfp[u], bip[u], bcp[u], bop[u]};

    // nonlinearity pair assignment (2 per lane):
    // quad0 -> rows 0,1 ; quad1 -> rows 4,5 ; quad2 -> rows 2,3 ; quad3 -> rows 6,7
    const int rowbase = (quad < 2) ? 4 * quad : 4 * (quad - 2) + 2;
    float c_st[2] = {0.0f, 0.0f};

    // ---- zero both A buffers (h(0)=0 and M-pad rows 8..15) ----
    for (int i = tid; i < 2 * 16 * ASTR; i += NTHR) ((short*)Abuf)[i] = 0;
    __syncthreads();

    // ---- x staging: thread tid -> (row6 = tid>>6, d6 = tid&63), all 512 threads ----
    const int row6 = tid >> 6, d6 = tid & 63;
    const float* xbase = xin + ((size_t)(blk * ROWS + row6) * T_SZ) * D_SZ + d6;
    Abuf[0][row6 * ASTR + d6] = f2bf(xbase[0]);
    float xv0 = xbase[1 * D_SZ];
    float xv1 = xbase[2 * D_SZ];
    __syncthreads();

    for (int t = 0; t < T_SZ; ++t) {
        const short* arow  = &Abuf[t & 1][nlo * ASTR + quad * 8];
        short*       anext = &Abuf[(t + 1) & 1][0];

        // prefetch x(t+3) from HBM (stays in flight across the lgkm-only barrier)
        int tt = t + 3; if (tt > T_SZ - 1) tt = T_SZ - 1;
        float xnext = xbase[(size_t)tt * D_SZ];

        // ---- A fragments + MFMA: 4 gate-tiles, 4 independent chains of 6 ----
        short8 a[6];
#pragma unroll
        for (int kt = 0; kt < 6; ++kt)
            a[kt] = *(const short8*)(arow + kt * 32);

        floatx4 acc[4];
#pragma unroll
        for (int g = 0; g < 4; ++g) acc[g] = (floatx4){0.f, 0.f, 0.f, 0.f};
#pragma unroll
        for (int kt = 0; kt < 6; ++kt) {
#pragma unroll
            for (int g = 0; g < 4; ++g)
                acc[g] = __builtin_amdgcn_mfma_f32_16x16x32_bf16(a[kt], bfr[g][kt], acc[g], 0, 0, 0);
        }

        // stage x(t+1) into next buffer (off the critical chain)
        if (t < T_SZ - 1) anext[row6 * ASTR + d6] = f2bf(xv0);
        xv0 = xv1;
        xv1 = xnext;

        // ---- redistribute rows 2,3,6,7 to quads 2,3 (valid data lives in quads 0,1) ----
        float sh[4][2];
#pragma unroll
        for (int g = 0; g < 4; ++g) {
#pragma unroll
            for (int p = 0; p < 2; ++p)
                sh[g][p] = __shfl_xor(acc[g][p + 2], 32);
        }

        // ---- nonlinearity + state update: 2 (row,u) pairs per lane ----
#pragma unroll
        for (int p = 0; p < 2; ++p) {
            const int row = rowbase + p;
            float gf = ((quad < 2) ? acc[0][p] : sh[0][p]) + bias[0];
            float gi = ((quad < 2) ? acc[1][p] : sh[1][p]) + bias[1];
            float gc = ((quad < 2) ? acc[2][p] : sh[2][p]) + bias[2];
            float go = ((quad < 2) ? acc[3][p] : sh[3][p]) + bias[3];
            float f  = fsig(gf);
            float ii = fsig(gi);
            float oo = fsig(go);
            float ct = ftanh(gc);
            c_st[p] = f * c_st[p] + ii * ct;
            float h = oo * ftanh(c_st[p]);
            if (t == T_SZ - 1) {
                out[(size_t)(blk * ROWS + row) * U_SZ + u] = h;
            } else {
                anext[row * ASTR + D_SZ + u] = f2bf(h);
            }
        }

        sync_lds();   // lgkmcnt-only barrier: h(t+1)/x(t+1) visible, vm prefetch unbroken
    }
}

extern "C" void kernel_launch(void* const* d_in, const int* in_sizes, int n_in,
                              void* d_out, int out_size, void* d_ws, size_t ws_size,
                              hipStream_t stream) {
    (void)in_sizes; (void)n_in; (void)d_ws; (void)ws_size; (void)out_size;
    const float* xin = (const float*)d_in[0];
    const float* Wf  = (const float*)d_in[1];
    const float* Uf  = (const float*)d_in[2];
    const float* bf  = (const float*)d_in[3];
    const float* Wi  = (const float*)d_in[4];
    const float* Ui  = (const float*)d_in[5];
    const float* bi  = (const float*)d_in[6];
    const float* Wc  = (const float*)d_in[7];
    const float* Uc  = (const float*)d_in[8];
    const float* bc  = (const float*)d_in[9];
    const float* Wo  = (const float*)d_in[10];
    const float* Uo  = (const float*)d_in[11];
    const float* bo  = (const float*)d_in[12];
    float* out = (float*)d_out;

    hipLaunchKernelGGL(lstm_persistent, dim3(NBLK), dim3(NTHR), 0, stream,
                       xin, Wf, Uf, bf, Wi, Ui, bi, Wc, Uc, bc, Wo, Uo, bo, out);
}

// Round 3
// 855.479 us; speedup vs baseline: 1.4626x; 1.1761x over previous
//
#include <hip/hip_runtime.h>
#include <stdint.h>

// ManualLSTM: B=512, T=1024, D=64, U=128.
// R3: 256 blocks x 256 threads (4 waves), 2 batch rows/block -> full 256-CU chip.
// Wave w owns u in [32w, 32w+32) for all 4 gates (8 N-tiles, 48 MFMAs).
// The 2 batch rows are replicated across all 16 M-slots of the MFMA tile via
// LDS read addressing (lane reads A-row nlo&1, broadcast) so EVERY lane holds
// both rows' gate sums in acc regs 0/1 -> per-lane extraction by cndmask
// select only: no shuffles, no gate LDS round-trip. Weights live in VGPRs.
// One lgkmcnt-only barrier per step (x HBM prefetch stays in flight).

typedef __attribute__((ext_vector_type(8))) short short8;
typedef __attribute__((ext_vector_type(4))) float floatx4;

#define B_SZ   512
#define T_SZ   1024
#define D_SZ   64
#define U_SZ   128
#define ROWS   2              // batch rows per block
#define NBLK   (B_SZ / ROWS)  // 256 blocks
#define NTHR   256            // 4 waves
#define ASTR   200            // A row stride in bf16 (192 + 8 pad; rows 16B-aligned)

__device__ __forceinline__ short f2bf(float f) {
    uint32_t u = __builtin_bit_cast(uint32_t, f);
    uint32_t r = (u + 0x7fffu + ((u >> 16) & 1u)) >> 16;   // RNE
    return (short)r;
}

__device__ __forceinline__ float fsig(float x) {
    return __builtin_amdgcn_rcpf(1.0f + __builtin_amdgcn_exp2f(-1.4426950408889634f * x));
}
__device__ __forceinline__ float ftanh(float x) {
    return 1.0f - 2.0f * __builtin_amdgcn_rcpf(1.0f + __builtin_amdgcn_exp2f(2.8853900817779268f * x));
}

// barrier draining only LDS ops (NOT vmcnt -> global x prefetch stays in flight)
__device__ __forceinline__ void sync_lds() {
    asm volatile("s_waitcnt lgkmcnt(0)\n\ts_barrier" ::: "memory");
}

__global__ __launch_bounds__(NTHR, 1) void lstm_persistent(
    const float* __restrict__ xin,
    const float* __restrict__ Wf, const float* __restrict__ Uf, const float* __restrict__ bfp,
    const float* __restrict__ Wi, const float* __restrict__ Ui, const float* __restrict__ bip,
    const float* __restrict__ Wc, const float* __restrict__ Uc, const float* __restrict__ bcp,
    const float* __restrict__ Wo, const float* __restrict__ Uo, const float* __restrict__ bop,
    float* __restrict__ out)
{
    __shared__ short Abuf[2][ROWS * ASTR];   // [buf][row 0..1][k 0..191] bf16

    const int tid  = threadIdx.x;
    const int wave = tid >> 6;     // 0..3
    const int lane = tid & 63;
    const int quad = lane >> 4;    // 0..3
    const int nlo  = lane & 15;
    const int blk  = blockIdx.x;

    // this lane's (row, u) pair for the nonlinearity/state update:
    const int prow = quad >> 1;                      // 0..1
    const int ti_s = quad & 1;                       // which u-tile of the wave
    const int u    = 32 * wave + ti_s * 16 + nlo;    // 0..127

    // ---- static weight B-fragments in VGPRs: bfr[gate][ti][kt] ----
    // B layout (16x16x32): B[k = quad*8 + j][n = lane&15]; tile ti col = 32w + 16ti + n
    const float* Wg[4] = {Wf, Wi, Wc, Wo};
    const float* Ug[4] = {Uf, Ui, Uc, Uo};
    short8 bfr[4][2][6];
#pragma unroll
    for (int g = 0; g < 4; ++g) {
#pragma unroll
        for (int ti = 0; ti < 2; ++ti) {
            const int uc = 32 * wave + ti * 16 + nlo;
#pragma unroll
            for (int kt = 0; kt < 6; ++kt) {
#pragma unroll
                for (int j = 0; j < 8; ++j) {
                    int k = kt * 32 + quad * 8 + j;   // 0..191
                    float w = (k < D_SZ) ? Wg[g][k * U_SZ + uc]
                                         : Ug[g][(k - D_SZ) * U_SZ + uc];
                    bfr[g][ti][kt][j] = f2bf(w);
                }
            }
        }
    }
    const float bias[4] = {bfp[u], bip[u], bcp[u], bop[u]};
    float c_st = 0.0f;

    // ---- zero both A buffers (h(0) = 0) ----
    for (int i = tid; i < 2 * ROWS * ASTR; i += NTHR) ((short*)Abuf)[i] = 0;
    __syncthreads();

    // ---- x staging: threads 0..127 -> (row = tid>>6, d = tid&63) ----
    const int row6 = (tid >> 6) & 1, d6 = tid & 63;
    const bool xthr = (tid < 128);
    const float* xbase = xin + ((size_t)(blk * ROWS + row6) * T_SZ) * D_SZ + d6;
    float xv0 = 0.f, xv1 = 0.f;
    if (xthr) {
        Abuf[0][row6 * ASTR + d6] = f2bf(xbase[0]);
        xv0 = xbase[1 * D_SZ];
        xv1 = xbase[2 * D_SZ];
    }
    __syncthreads();

    // A-operand read: lane supplies M-row nlo -> batch row (nlo&1) (replication)
    for (int t = 0; t < T_SZ; ++t) {
        const short* arow  = &Abuf[t & 1][(nlo & 1) * ASTR + quad * 8];
        short*       anext = &Abuf[(t + 1) & 1][0];

        // prefetch x(t+3) (stays in flight across the lgkm-only barrier)
        float xnext = 0.f;
        if (xthr) {
            int tt = t + 3; if (tt > T_SZ - 1) tt = T_SZ - 1;
            xnext = xbase[(size_t)tt * D_SZ];
        }

        // ---- A fragments + 48 MFMAs (8 independent chains of 6) ----
        short8 a[6];
#pragma unroll
        for (int kt = 0; kt < 6; ++kt)
            a[kt] = *(const short8*)(arow + kt * 32);

        floatx4 acc[4][2];
#pragma unroll
        for (int g = 0; g < 4; ++g)
#pragma unroll
            for (int ti = 0; ti < 2; ++ti)
                acc[g][ti] = (floatx4){0.f, 0.f, 0.f, 0.f};
#pragma unroll
        for (int kt = 0; kt < 6; ++kt)
#pragma unroll
            for (int g = 0; g < 4; ++g)
#pragma unroll
                for (int ti = 0; ti < 2; ++ti)
                    acc[g][ti] = __builtin_amdgcn_mfma_f32_16x16x32_bf16(
                        a[kt], bfr[g][ti][kt], acc[g][ti], 0, 0, 0);

        // stage x(t+1) into next buffer (off the dependence chain)
        if (xthr && t < T_SZ - 1) anext[row6 * ASTR + d6] = f2bf(xv0);
        xv0 = xv1;
        xv1 = xnext;

        // ---- extract this lane's (prow, u) gate values: pure cndmask selects ----
        // C/D: col = lane&15, row_cd = quad*4 + reg; batch row = row_cd & 1 = reg & 1.
        float gv[4];
#pragma unroll
        for (int g = 0; g < 4; ++g) {
            float va = ti_s ? acc[g][1][0] : acc[g][0][0];   // batch row 0
            float vb = ti_s ? acc[g][1][1] : acc[g][0][1];   // batch row 1
            gv[g] = (prow ? vb : va) + bias[g];
        }

        // ---- nonlinearity + state update: exactly one (row,u) pair per lane ----
        float f  = fsig(gv[0]);
        float ii = fsig(gv[1]);
        float ct = ftanh(gv[2]);
        float oo = fsig(gv[3]);
        c_st = f * c_st + ii * ct;
        float h = oo * ftanh(c_st);
        if (t == T_SZ - 1) {
            out[(size_t)(blk * ROWS + prow) * U_SZ + u] = h;
        } else {
            anext[prow * ASTR + D_SZ + u] = f2bf(h);
        }

        sync_lds();   // h(t+1)/x(t+1) visible; vm prefetch unbroken
    }
}

extern "C" void kernel_launch(void* const* d_in, const int* in_sizes, int n_in,
                              void* d_out, int out_size, void* d_ws, size_t ws_size,
                              hipStream_t stream) {
    (void)in_sizes; (void)n_in; (void)d_ws; (void)ws_size; (void)out_size;
    const float* xin = (const float*)d_in[0];
    const float* Wf  = (const float*)d_in[1];
    const float* Uf  = (const float*)d_in[2];
    const float* bf  = (const float*)d_in[3];
    const float* Wi  = (const float*)d_in[4];
    const float* Ui  = (const float*)d_in[5];
    const float* bi  = (const float*)d_in[6];
    const float* Wc  = (const float*)d_in[7];
    const float* Uc  = (const float*)d_in[8];
    const float* bc  = (const float*)d_in[9];
    const float* Wo  = (const float*)d_in[10];
    const float* Uo  = (const float*)d_in[11];
    const float* bo  = (const float*)d_in[12];
    float* out = (float*)d_out;

    hipLaunchKernelGGL(lstm_persistent, dim3(NBLK), dim3(NTHR), 0, stream,
                       xin, Wf, Uf, bf, Wi, Ui, bi, Wc, Uc, bc, Wo, Uo, bo, out);
}

// Round 4
// 660.254 us; speedup vs baseline: 1.8951x; 1.2957x over previous
//
#include <hip/hip_runtime.h>
#include <stdint.h>

// ManualLSTM: B=512, T=1024, D=64, U=128.
// R4: 256 blocks x 512 threads (8 waves, 2 waves/SIMD), 2 batch rows/block.
// Key restructure vs R3:
//  - x.W projection is lifted out of the per-step GEMM: once per 8-step group,
//    one MFMA pass uses ALL 16 M-rows (8 future timesteps x 2 batch rows of x,
//    K=64) and spills xproj+bias to LDS Gx[16][128u][4gates] fp32.
//  - per-step recurrent GEMM is h.U only (K=128): 128 MFMAs/block-step
//    (+8 amortized) vs 192 -> per-SIMD MFMA floor ~660 cyc.
//  - wave w owns u in [16w,16w+16) for all 4 gates; A rows replicated via
//    lane addressing (nlo&1) so extraction is a per-lane reg select; gate
//    table read is one ds_read_b128 (4 gates contiguous).
//  - 2 waves/SIMD so VALU/trans of one wave hides under the other's MFMAs.
// One lgkm-only barrier per step; +1 barrier per 8 steps around the Gx spill.

typedef __attribute__((ext_vector_type(8))) short short8;
typedef __attribute__((ext_vector_type(4))) float floatx4;

#define B_SZ   512
#define T_SZ   1024
#define D_SZ   64
#define U_SZ   128
#define ROWS   2              // batch rows per block
#define NBLK   (B_SZ / ROWS)  // 256 blocks
#define NTHR   512            // 8 waves
#define A1STR  136            // h row stride (128 + 8 pad) in bf16
#define A2STR  72             // x row stride (64 + 8 pad) in bf16
#define GXSTR  520            // Gx row stride in fp32: 128u*4g + 8 pad

__device__ __forceinline__ short f2bf(float f) {
    uint32_t u = __builtin_bit_cast(uint32_t, f);
    uint32_t r = (u + 0x7fffu + ((u >> 16) & 1u)) >> 16;   // RNE
    return (short)r;
}
__device__ __forceinline__ float fsig(float x) {
    return __builtin_amdgcn_rcpf(1.0f + __builtin_amdgcn_exp2f(-1.4426950408889634f * x));
}
__device__ __forceinline__ float ftanh(float x) {
    return 1.0f - 2.0f * __builtin_amdgcn_rcpf(1.0f + __builtin_amdgcn_exp2f(2.8853900817779268f * x));
}
// barrier draining only LDS ops (NOT vmcnt -> global x prefetch stays in flight)
__device__ __forceinline__ void sync_lds() {
    asm volatile("s_waitcnt lgkmcnt(0)\n\ts_barrier" ::: "memory");
}

__global__ __launch_bounds__(NTHR, 2) void lstm_persistent(
    const float* __restrict__ xin,
    const float* __restrict__ Wf, const float* __restrict__ Uf, const float* __restrict__ bfp,
    const float* __restrict__ Wi, const float* __restrict__ Ui, const float* __restrict__ bip,
    const float* __restrict__ Wc, const float* __restrict__ Uc, const float* __restrict__ bcp,
    const float* __restrict__ Wo, const float* __restrict__ Uo, const float* __restrict__ bop,
    float* __restrict__ out)
{
    __shared__ float Gx[16 * GXSTR];        // xproj+bias table for current 8-step group
    __shared__ short A1[2][2 * A1STR];      // h (bf16), double-buffered by step parity
    __shared__ short A2[16 * A2STR];        // x tile for next group: row m = (t_off=m>>1, brow=m&1)

    const int tid  = threadIdx.x;
    const int wave = tid >> 6;     // 0..7
    const int lane = tid & 63;
    const int quad = lane >> 4;    // 0..3
    const int nlo  = lane & 15;
    const int blk  = blockIdx.x;

    const int  u      = 16 * wave + nlo;   // this lane's hidden unit, 0..127
    const int  prow   = quad >> 1;         // batch row this lane updates
    const bool writer = (quad & 1) == 0;   // dedup: quads 0,2 write h/out

    // ---- static weight B-fragments in VGPRs ----
    // B layout (16x16x32): B[k = quad*8 + j][n = lane&15]
    const float* Wg[4] = {Wf, Wi, Wc, Wo};
    const float* Ug[4] = {Uf, Ui, Uc, Uo};
    short8 bU[4][4];   // recurrent U, K=128
    short8 bW[4][2];   // input W, K=64 (group xproj pass)
#pragma unroll
    for (int g = 0; g < 4; ++g) {
#pragma unroll
        for (int kt = 0; kt < 4; ++kt)
#pragma unroll
            for (int j = 0; j < 8; ++j) {
                int k = kt * 32 + quad * 8 + j;
                bU[g][kt][j] = f2bf(Ug[g][k * U_SZ + u]);
            }
#pragma unroll
        for (int kt = 0; kt < 2; ++kt)
#pragma unroll
            for (int j = 0; j < 8; ++j) {
                int k = kt * 32 + quad * 8 + j;
                bW[g][kt][j] = f2bf(Wg[g][k * U_SZ + u]);
            }
    }
    const float bias4[4] = {bfp[u], bip[u], bcp[u], bop[u]};
    float c_st = 0.0f;

    // ---- x loader mapping: thread -> one float2 of the 16x64 x-tile ----
    const int xrow = tid >> 8;             // 0..1
    const int xj   = (tid >> 5) & 7;       // t offset in group
    const int xd   = (tid & 31) << 1;      // d (pairs)
    const float* xb = xin + ((size_t)(blk * ROWS + xrow) * T_SZ) * D_SZ + xd;

    // ---- prologue ----
    for (int i = tid; i < 2 * 2 * A1STR; i += NTHR) ((short*)A1)[i] = 0;   // h(0)=0
    {   // stage x(group 0) into A2
        float2 v = *(const float2*)(xb + (size_t)xj * D_SZ);
        short2 p; p.x = f2bf(v.x); p.y = f2bf(v.y);
        *(short2*)&A2[(2 * xj + xrow) * A2STR + xd] = p;
    }
    __syncthreads();
    {   // seed Gx with xproj(group 0) + bias
        const short* a2p = &A2[nlo * A2STR + quad * 8];
        short8 s0 = *(const short8*)a2p, s1 = *(const short8*)(a2p + 32);
        floatx4 q[4];
#pragma unroll
        for (int g = 0; g < 4; ++g) {
            q[g] = (floatx4){0.f, 0.f, 0.f, 0.f};
            q[g] = __builtin_amdgcn_mfma_f32_16x16x32_bf16(s0, bW[g][0], q[g], 0, 0, 0);
            q[g] = __builtin_amdgcn_mfma_f32_16x16x32_bf16(s1, bW[g][1], q[g], 0, 0, 0);
        }
#pragma unroll
        for (int r = 0; r < 4; ++r) {
            floatx4 wv = {q[0][r] + bias4[0], q[1][r] + bias4[1],
                          q[2][r] + bias4[2], q[3][r] + bias4[3]};
            *(floatx4*)&Gx[(quad * 4 + r) * GXSTR + 4 * u] = wv;
        }
    }
    // prefetch x(group 1) into regs
    float2 xr = *(const float2*)(xb + (size_t)(8 + xj) * D_SZ);
    __syncthreads();

    for (int g = 0; g < 128; ++g) {
#pragma unroll
        for (int j = 0; j < 8; ++j) {
            const int s = g * 8 + j;

            // stage x(g+1) into A2 (consumed at this group's j==7 seed)
            if (j == 0 && g < 127) {
                short2 p; p.x = f2bf(xr.x); p.y = f2bf(xr.y);
                *(short2*)&A2[(2 * xj + xrow) * A2STR + xd] = p;
            }
            // issue HBM prefetch of x(g+2); stays in flight across lgkm barriers
            if (j == 2 && g < 126) {
                xr = *(const float2*)(xb + (size_t)(8 * (g + 2) + xj) * D_SZ);
            }

            // ---- recurrent GEMM: h(t).U, K=128, rows replicated via (nlo&1) ----
            const short* ap = &A1[j & 1][(nlo & 1) * A1STR + quad * 8];
            short8 a0 = *(const short8*)(ap);
            short8 a1 = *(const short8*)(ap + 32);
            short8 a2 = *(const short8*)(ap + 64);
            short8 a3 = *(const short8*)(ap + 96);
            floatx4 acc[4];
#pragma unroll
            for (int gt = 0; gt < 4; ++gt) {
                acc[gt] = (floatx4){0.f, 0.f, 0.f, 0.f};
                acc[gt] = __builtin_amdgcn_mfma_f32_16x16x32_bf16(a0, bU[gt][0], acc[gt], 0, 0, 0);
                acc[gt] = __builtin_amdgcn_mfma_f32_16x16x32_bf16(a1, bU[gt][1], acc[gt], 0, 0, 0);
                acc[gt] = __builtin_amdgcn_mfma_f32_16x16x32_bf16(a2, bU[gt][2], acc[gt], 0, 0, 0);
                acc[gt] = __builtin_amdgcn_mfma_f32_16x16x32_bf16(a3, bU[gt][3], acc[gt], 0, 0, 0);
            }

            // ---- gate table read: xproj+bias for (t, prow), 4 gates contiguous ----
            floatx4 gx = *(const floatx4*)&Gx[(2 * j + prow) * GXSTR + 4 * u];

            // ---- gates + state update (C/D row parity = batch row) ----
            float gv0 = (prow ? acc[0][1] : acc[0][0]) + gx[0];
            float gv1 = (prow ? acc[1][1] : acc[1][0]) + gx[1];
            float gv2 = (prow ? acc[2][1] : acc[2][0]) + gx[2];
            float gv3 = (prow ? acc[3][1] : acc[3][0]) + gx[3];
            float f  = fsig(gv0);
            float ii = fsig(gv1);
            float ct = ftanh(gv2);
            float oo = fsig(gv3);
            c_st = f * c_st + ii * ct;
            float h = oo * ftanh(c_st);
            if (s == T_SZ - 1) {
                if (writer) out[(size_t)(blk * ROWS + prow) * U_SZ + u] = h;
            } else if (writer) {
                A1[(j & 1) ^ 1][prow * A1STR + u] = f2bf(h);
            }

            // ---- group boundary: xproj GEMM for next group, spill to Gx ----
            if (j == 7 && g < 127) {
                const short* a2p = &A2[nlo * A2STR + quad * 8];
                short8 s0 = *(const short8*)a2p, s1 = *(const short8*)(a2p + 32);
                floatx4 q[4];
#pragma unroll
                for (int gt = 0; gt < 4; ++gt) {
                    q[gt] = (floatx4){0.f, 0.f, 0.f, 0.f};
                    q[gt] = __builtin_amdgcn_mfma_f32_16x16x32_bf16(s0, bW[gt][0], q[gt], 0, 0, 0);
                    q[gt] = __builtin_amdgcn_mfma_f32_16x16x32_bf16(s1, bW[gt][1], q[gt], 0, 0, 0);
                }
                sync_lds();   // all waves' Gx reads (this group) complete
#pragma unroll
                for (int r = 0; r < 4; ++r) {
                    floatx4 wv = {q[0][r] + bias4[0], q[1][r] + bias4[1],
                                  q[2][r] + bias4[2], q[3][r] + bias4[3]};
                    *(floatx4*)&Gx[(quad * 4 + r) * GXSTR + 4 * u] = wv;
                }
            }

            sync_lds();   // h(t+1)/A2/Gx visible; vm prefetch unbroken
        }
    }
}

extern "C" void kernel_launch(void* const* d_in, const int* in_sizes, int n_in,
                              void* d_out, int out_size, void* d_ws, size_t ws_size,
                              hipStream_t stream) {
    (void)in_sizes; (void)n_in; (void)d_ws; (void)ws_size; (void)out_size;
    const float* xin = (const float*)d_in[0];
    const float* Wf  = (const float*)d_in[1];
    const float* Uf  = (const float*)d_in[2];
    const float* bf  = (const float*)d_in[3];
    const float* Wi  = (const float*)d_in[4];
    const float* Ui  = (const float*)d_in[5];
    const float* bi  = (const float*)d_in[6];
    const float* Wc  = (const float*)d_in[7];
    const float* Uc  = (const float*)d_in[8];
    const float* bc  = (const float*)d_in[9];
    const float* Wo  = (const float*)d_in[10];
    const float* Uo  = (const float*)d_in[11];
    const float* bo  = (const float*)d_in[12];
    float* out = (float*)d_out;

    hipLaunchKernelGGL(lstm_persistent, dim3(NBLK), dim3(NTHR), 0, stream,
                       xin, Wf, Uf, bf, Wi, Ui, bi, Wc, Uc, bc, Wo, Uo, bo, out);
}

// Round 5
// 581.915 us; speedup vs baseline: 2.1502x; 1.1346x over previous
//
#include <hip/hip_runtime.h>
#include <stdint.h>

// ManualLSTM: B=512, T=1024, D=64, U=128.
// R5: 256 blocks x 512 threads (8 waves, 2 waves/SIMD), 2 batch rows/block.
// vs R4: the per-step recurrent GEMM h(t).U (K=128) now uses ONE MX-scaled
// fp8 MFMA per gate (v_mfma_scale_f32_16x16x128_f8f6f4, unity e8m0 scales):
//   32 MFMAs/block-step x 8.64cyc = ~277 cyc vs bf16's ~620.
// h is stored in LDS as fp8-e4m3 bytes (A-side), U-weights quantized once to
// fp8 B-fragments in VGPRs. xproj (x.W, K=64) stays bf16 MFMA once per
// 8-step group into LDS table Gx (fp32, +bias). GXSTR=524 kills the 4-way
// spill-bank conflict R4 had. One lgkm-only barrier/step.

typedef __attribute__((ext_vector_type(8))) short short8;
typedef __attribute__((ext_vector_type(4))) float floatx4;
typedef __attribute__((ext_vector_type(4))) int   intx4;
typedef __attribute__((ext_vector_type(8))) int   intx8;

#define B_SZ   512
#define T_SZ   1024
#define D_SZ   64
#define U_SZ   128
#define ROWS   2              // batch rows per block
#define NBLK   (B_SZ / ROWS)  // 256 blocks
#define NTHR   512            // 8 waves
#define A1STRB 160            // h row stride in BYTES (128 fp8 + 32 pad)
#define A2STR  72             // x row stride (64 + 8 pad) in bf16
#define GXSTR  524            // Gx row stride in fp32 (4*GXSTR%32 = 16 -> 2-way max)

__device__ __forceinline__ short f2bf(float f) {
    uint32_t u = __builtin_bit_cast(uint32_t, f);
    uint32_t r = (u + 0x7fffu + ((u >> 16) & 1u)) >> 16;   // RNE
    return (short)r;
}
__device__ __forceinline__ float fsig(float x) {
    return __builtin_amdgcn_rcpf(1.0f + __builtin_amdgcn_exp2f(-1.4426950408889634f * x));
}
__device__ __forceinline__ float ftanh(float x) {
    return 1.0f - 2.0f * __builtin_amdgcn_rcpf(1.0f + __builtin_amdgcn_exp2f(2.8853900817779268f * x));
}
// barrier draining only LDS ops (NOT vmcnt -> global x prefetch stays in flight)
__device__ __forceinline__ void sync_lds() {
    asm volatile("s_waitcnt lgkmcnt(0)\n\ts_barrier" ::: "memory");
}

__global__ __launch_bounds__(NTHR, 2) void lstm_persistent(
    const float* __restrict__ xin,
    const float* __restrict__ Wf, const float* __restrict__ Uf, const float* __restrict__ bfp,
    const float* __restrict__ Wi, const float* __restrict__ Ui, const float* __restrict__ bip,
    const float* __restrict__ Wc, const float* __restrict__ Uc, const float* __restrict__ bcp,
    const float* __restrict__ Wo, const float* __restrict__ Uo, const float* __restrict__ bop,
    float* __restrict__ out)
{
    __shared__ float Gx[16 * GXSTR];                 // xproj+bias table (fp32)
    __shared__ __align__(16) char A1[2][2 * A1STRB]; // h as fp8-e4m3, dbuf by step parity
    __shared__ short A2[16 * A2STR];                 // x tile (bf16) for next group

    const int tid  = threadIdx.x;
    const int wave = tid >> 6;     // 0..7
    const int lane = tid & 63;
    const int quad = lane >> 4;    // 0..3
    const int nlo  = lane & 15;
    const int blk  = blockIdx.x;

    const int  u      = 16 * wave + nlo;   // this lane's hidden unit, 0..127
    const int  prow   = quad >> 1;         // batch row this lane updates
    const bool writer = (quad & 1) == 0;   // quads 0,2 write h/out

    const float* Wg[4] = {Wf, Wi, Wc, Wo};
    const float* Ug[4] = {Uf, Ui, Uc, Uo};

    // ---- recurrent U as fp8 B-fragments (VGPRs): byte j of dword d = k = quad*32+4d+j ----
    intx8 bU8[4];
#pragma unroll
    for (int g = 0; g < 4; ++g) {
#pragma unroll
        for (int d = 0; d < 8; ++d) {
            const int k0 = quad * 32 + d * 4;
            float w0 = Ug[g][(k0 + 0) * U_SZ + u];
            float w1 = Ug[g][(k0 + 1) * U_SZ + u];
            float w2 = Ug[g][(k0 + 2) * U_SZ + u];
            float w3 = Ug[g][(k0 + 3) * U_SZ + u];
            int pk = __builtin_amdgcn_cvt_pk_fp8_f32(w0, w1, 0, 0);
            pk     = __builtin_amdgcn_cvt_pk_fp8_f32(w2, w3, pk, 1);
            bU8[g][d] = pk;
        }
    }
    // ---- input W as bf16 B-fragments (group xproj pass, K=64) ----
    short8 bW[4][2];
#pragma unroll
    for (int g = 0; g < 4; ++g)
#pragma unroll
        for (int kt = 0; kt < 2; ++kt)
#pragma unroll
            for (int j = 0; j < 8; ++j) {
                int k = kt * 32 + quad * 8 + j;
                bW[g][kt][j] = f2bf(Wg[g][k * U_SZ + u]);
            }
    const float bias4[4] = {bfp[u], bip[u], bcp[u], bop[u]};
    float c_st = 0.0f;

    // ---- x loader mapping: thread -> one float2 of the 16x64 x-tile ----
    const int xrow = tid >> 8;             // 0..1
    const int xj   = (tid >> 5) & 7;       // t offset in group
    const int xd   = (tid & 31) << 1;      // d (pairs)
    const float* xb = xin + ((size_t)(blk * ROWS + xrow) * T_SZ) * D_SZ + xd;

    // ---- prologue ----
    for (int i = tid; i < 2 * 2 * A1STRB; i += NTHR) ((char*)A1)[i] = 0;   // h(0)=0 (fp8 0x00)
    {   // stage x(group 0) into A2
        float2 v = *(const float2*)(xb + (size_t)xj * D_SZ);
        short2 p; p.x = f2bf(v.x); p.y = f2bf(v.y);
        *(short2*)&A2[(2 * xj + xrow) * A2STR + xd] = p;
    }
    __syncthreads();
    {   // seed Gx with xproj(group 0) + bias
        const short* a2p = &A2[nlo * A2STR + quad * 8];
        short8 s0 = *(const short8*)a2p, s1 = *(const short8*)(a2p + 32);
        floatx4 q[4];
#pragma unroll
        for (int g = 0; g < 4; ++g) {
            q[g] = (floatx4){0.f, 0.f, 0.f, 0.f};
            q[g] = __builtin_amdgcn_mfma_f32_16x16x32_bf16(s0, bW[g][0], q[g], 0, 0, 0);
            q[g] = __builtin_amdgcn_mfma_f32_16x16x32_bf16(s1, bW[g][1], q[g], 0, 0, 0);
        }
#pragma unroll
        for (int r = 0; r < 4; ++r) {
            floatx4 wv = {q[0][r] + bias4[0], q[1][r] + bias4[1],
                          q[2][r] + bias4[2], q[3][r] + bias4[3]};
            *(floatx4*)&Gx[(quad * 4 + r) * GXSTR + 4 * u] = wv;
        }
    }
    float2 xr = *(const float2*)(xb + (size_t)(8 + xj) * D_SZ);   // x(group 1)
    __syncthreads();

    for (int g = 0; g < 128; ++g) {
#pragma unroll
        for (int j = 0; j < 8; ++j) {
            const int s = g * 8 + j;

            // stage x(g+1) into A2 (consumed at this group's j==7 seed)
            if (j == 0 && g < 127) {
                short2 p; p.x = f2bf(xr.x); p.y = f2bf(xr.y);
                *(short2*)&A2[(2 * xj + xrow) * A2STR + xd] = p;
            }
            // HBM prefetch x(g+2); stays in flight across lgkm barriers
            if (j == 2 && g < 126) {
                xr = *(const float2*)(xb + (size_t)(8 * (g + 2) + xj) * D_SZ);
            }

            // ---- recurrent GEMM: h(t).U, ONE scaled fp8 MFMA per gate (K=128) ----
            // A fragment: lane (quad,nlo) holds h[row = nlo&1][k = quad*32 + 0..31]
            const char* ap = &A1[j & 1][(nlo & 1) * A1STRB + quad * 32];
            intx4 alo = *(const intx4*)(ap);
            intx4 ahi = *(const intx4*)(ap + 16);
            intx8 a8 = {alo.x, alo.y, alo.z, alo.w, ahi.x, ahi.y, ahi.z, ahi.w};

            floatx4 acc[4];
#pragma unroll
            for (int gt = 0; gt < 4; ++gt) {
                floatx4 z = (floatx4){0.f, 0.f, 0.f, 0.f};
                acc[gt] = __builtin_amdgcn_mfma_scale_f32_16x16x128_f8f6f4(
                    a8, bU8[gt], z, 0, 0,
                    0, 0x7f7f7f7f,    // A: e8m0 scales = 1.0
                    0, 0x7f7f7f7f);   // B: e8m0 scales = 1.0
            }

            // ---- gate table read: xproj+bias for (t, prow), 4 gates contiguous ----
            floatx4 gx = *(const floatx4*)&Gx[(2 * j + prow) * GXSTR + 4 * u];

            // ---- gates + state update (C/D row parity = batch row) ----
            float gv0 = (prow ? acc[0][1] : acc[0][0]) + gx[0];
            float gv1 = (prow ? acc[1][1] : acc[1][0]) + gx[1];
            float gv2 = (prow ? acc[2][1] : acc[2][0]) + gx[2];
            float gv3 = (prow ? acc[3][1] : acc[3][0]) + gx[3];
            float f  = fsig(gv0);
            float ii = fsig(gv1);
            float ct = ftanh(gv2);
            float oo = fsig(gv3);
            c_st = f * c_st + ii * ct;
            float h = oo * ftanh(c_st);

            // h -> fp8 byte pair (even lane packs self+neighbor), 2-way-free write
            float hnb = __shfl_xor(h, 1);
            if (s == T_SZ - 1) {
                if (writer) out[(size_t)(blk * ROWS + prow) * U_SZ + u] = h;
            } else if (writer && (nlo & 1) == 0) {
                int pk = __builtin_amdgcn_cvt_pk_fp8_f32(h, hnb, 0, 0);
                *(short*)&A1[(j & 1) ^ 1][prow * A1STRB + u] = (short)(pk & 0xffff);
            }

            // ---- group boundary: xproj GEMM for next group, spill to Gx ----
            if (j == 7 && g < 127) {
                const short* a2p = &A2[nlo * A2STR + quad * 8];
                short8 s0 = *(const short8*)a2p, s1 = *(const short8*)(a2p + 32);
                floatx4 q[4];
#pragma unroll
                for (int gt = 0; gt < 4; ++gt) {
                    q[gt] = (floatx4){0.f, 0.f, 0.f, 0.f};
                    q[gt] = __builtin_amdgcn_mfma_f32_16x16x32_bf16(s0, bW[gt][0], q[gt], 0, 0, 0);
                    q[gt] = __builtin_amdgcn_mfma_f32_16x16x32_bf16(s1, bW[gt][1], q[gt], 0, 0, 0);
                }
                sync_lds();   // all waves' Gx reads (this group) complete
#pragma unroll
                for (int r = 0; r < 4; ++r) {
                    floatx4 wv = {q[0][r] + bias4[0], q[1][r] + bias4[1],
                                  q[2][r] + bias4[2], q[3][r] + bias4[3]};
                    *(floatx4*)&Gx[(quad * 4 + r) * GXSTR + 4 * u] = wv;
                }
            }

            sync_lds();   // h(t+1)/A2/Gx visible; vm prefetch unbroken
        }
    }
}

extern "C" void kernel_launch(void* const* d_in, const int* in_sizes, int n_in,
                              void* d_out, int out_size, void* d_ws, size_t ws_size,
                              hipStream_t stream) {
    (void)in_sizes; (void)n_in; (void)d_ws; (void)ws_size; (void)out_size;
    const float* xin = (const float*)d_in[0];
    const float* Wf  = (const float*)d_in[1];
    const float* Uf  = (const float*)d_in[2];
    const float* bf  = (const float*)d_in[3];
    const float* Wi  = (const float*)d_in[4];
    const float* Ui  = (const float*)d_in[5];
    const float* bi  = (const float*)d_in[6];
    const float* Wc  = (const float*)d_in[7];
    const float* Uc  = (const float*)d_in[8];
    const float* bc  = (const float*)d_in[9];
    const float* Wo  = (const float*)d_in[10];
    const float* Uo  = (const float*)d_in[11];
    const float* bo  = (const float*)d_in[12];
    float* out = (float*)d_out;

    hipLaunchKernelGGL(lstm_persistent, dim3(NBLK), dim3(NTHR), 0, stream,
                       xin, Wf, Uf, bf, Wi, Ui, bi, Wc, Uc, bc, Wo, Uo, bo, out);
}